// Round 11
// baseline (721.408 us; speedup 1.0000x reference)
//
#include <hip/hip_runtime.h>
#include <math.h>

#define N_NODES 50000
#define D 160
#define H 5
#define C 32
#define HC 160
#define E_EDGES 800000
#define ED 16
#define HID 512
#define EPS 1e-5f
#define NEG_SLOPE 0.2f

typedef __attribute__((ext_vector_type(8))) short bf16x8;
typedef __attribute__((ext_vector_type(4))) float f32x4;
typedef __attribute__((ext_vector_type(4))) short short4v;

__device__ inline float bf2f(short s) {
  unsigned u = ((unsigned)(unsigned short)s) << 16;
  return __builtin_bit_cast(float, u);
}
__device__ inline short f2bf(float f) {
  unsigned u = __builtin_bit_cast(unsigned, f);
  u = u + 0x7fffu + ((u >> 16) & 1u);
  return (short)(u >> 16);
}
__device__ inline float selu_f(float v) {
  return 1.0507009873554805f * (v > 0.f ? v : 1.6732632423543772f * (__expf(v) - 1.f));
}

// ---------------- weight prep: transpose + bf16 (+ padded WeT) ----------------
__global__ void prep_weights(const float* __restrict__ Wl, const float* __restrict__ Wr,
                             const float* __restrict__ Wm1, const float* __restrict__ Wm2,
                             const float* __restrict__ We,
                             short* __restrict__ WlT, short* __restrict__ WrT,
                             short* __restrict__ W1T, short* __restrict__ W2T,
                             short* __restrict__ WeTp) {
  int i = blockIdx.x * blockDim.x + threadIdx.x;
  if (i < 25600) { int n = i / 160, k = i % 160; WlT[n*160 + k] = f2bf(Wl[k*160 + n]); return; }
  i -= 25600;
  if (i < 25600) { int n = i / 160, k = i % 160; WrT[n*160 + k] = f2bf(Wr[k*160 + n]); return; }
  i -= 25600;
  if (i < 81920) { int n = i / 160, k = i % 160; W1T[n*160 + k] = f2bf(Wm1[k*512 + n]); return; }
  i -= 81920;
  if (i < 81920) { int n = i / 512, k = i % 512; W2T[n*512 + k] = f2bf(Wm2[k*160 + n]); return; }
  i -= 81920;
  if (i < 5120) { int col = i / 32, k = i % 32;
    WeTp[col*32 + k] = (k < ED) ? f2bf(We[k*160 + col]) : (short)0; }
}

// ---------------- CSR build ----------------
__global__ void count_kernel(const int* __restrict__ ei, int* __restrict__ cnt) {
  int e = blockIdx.x * blockDim.x + threadIdx.x;
  if (e < E_EDGES) atomicAdd(&cnt[ei[E_EDGES + e]], 1);
}

__global__ __launch_bounds__(1024) void scanA(const int* __restrict__ cnt,
                                              int* __restrict__ pinc, int* __restrict__ bsum) {
  int b = blockIdx.x, t = threadIdx.x;
  int i = b * 1024 + t;
  int v = (i < N_NODES) ? cnt[i] : 0;
  int lane = t & 63, wid = t >> 6;
  int s = v;
#pragma unroll
  for (int off = 1; off < 64; off <<= 1) {
    int u = __shfl_up(s, off, 64);
    if (lane >= off) s += u;
  }
  __shared__ int ws[16];
  if (lane == 63) ws[wid] = s;
  __syncthreads();
  if (wid == 0) {
    int w = (lane < 16) ? ws[lane] : 0;
#pragma unroll
    for (int off = 1; off < 16; off <<= 1) {
      int u = __shfl_up(w, off, 64);
      if (lane >= off) w += u;
    }
    if (lane < 16) ws[lane] = w;
  }
  __syncthreads();
  int incl = s + (wid > 0 ? ws[wid - 1] : 0);
  if (i < N_NODES) pinc[i] = incl;
  if (t == 1023) bsum[b] = incl;
}

__global__ void scanB(const int* __restrict__ bsum, int* __restrict__ boff) {
  int t = threadIdx.x;
  int v = (t < 49) ? bsum[t] : 0;
  int s = v;
#pragma unroll
  for (int off = 1; off < 64; off <<= 1) {
    int u = __shfl_up(s, off, 64);
    if (t >= off) s += u;
  }
  if (t < 49) boff[t] = s - v;
}

__global__ __launch_bounds__(1024) void scanC(const int* __restrict__ pinc,
                                              const int* __restrict__ boff,
                                              int* __restrict__ offs) {
  int b = blockIdx.x, t = threadIdx.x;
  int i = b * 1024 + t;
  if (i < N_NODES) offs[i + 1] = pinc[i] + boff[b];
  if (i == 0) offs[0] = 0;
}

// scatter: CSR-order src*160, bf16 edge_attr
__global__ void scatter3(const int* __restrict__ ei, const float* __restrict__ eattr,
                         const int* __restrict__ offs, int* __restrict__ cursor,
                         int* __restrict__ srcm, short* __restrict__ eacsr) {
  int e = blockIdx.x * blockDim.x + threadIdx.x;
  if (e < E_EDGES) {
    int dst = ei[E_EDGES + e];
    int src = ei[e];
    int slot = atomicAdd(&cursor[dst], 1);
    int j = offs[dst] + slot;
    srcm[j] = src * 160;
    const float4* s = (const float4*)&eattr[(size_t)e * ED];
    float4 v0 = s[0], v1 = s[1], v2 = s[2], v3 = s[3];
    short* o = eacsr + (size_t)j * ED;
    short4v w0, w1, w2, w3;
    w0[0]=f2bf(v0.x); w0[1]=f2bf(v0.y); w0[2]=f2bf(v0.z); w0[3]=f2bf(v0.w);
    w1[0]=f2bf(v1.x); w1[1]=f2bf(v1.y); w1[2]=f2bf(v1.z); w1[3]=f2bf(v1.w);
    w2[0]=f2bf(v2.x); w2[1]=f2bf(v2.y); w2[2]=f2bf(v2.z); w2[3]=f2bf(v2.w);
    w3[0]=f2bf(v3.x); w3[1]=f2bf(v3.y); w3[2]=f2bf(v3.z); w3[3]=f2bf(v3.w);
    *(short4v*)(o + 0) = w0; *(short4v*)(o + 4) = w1;
    *(short4v*)(o + 8) = w2; *(short4v*)(o + 12) = w3;
  }
}

// ---------------- proj: xl = x@Wl+bl, xr = x@Wr+br (fp32 in, bf16 out) ----------
__global__ __launch_bounds__(256) void proj_mfma(
    const float* __restrict__ x, const short* __restrict__ WlT, const short* __restrict__ WrT,
    const float* __restrict__ bl, const float* __restrict__ br,
    short* __restrict__ xl, short* __restrict__ xr)
{
  int t = threadIdx.x;
  int wave = t >> 6, lane = t & 63;
  int lq = lane >> 4, lc = lane & 15;
  int row0 = blockIdx.x * 64 + wave * 16;
  f32x4 accl[10] = {}, accr[10] = {};
#pragma unroll
  for (int kt = 0; kt < 5; ++kt) {
    int gr = min(row0 + lc, N_NODES - 1);
    const float4* pa = (const float4*)&x[(size_t)gr * 160 + kt * 32 + lq * 8];
    float4 a0 = pa[0], a1 = pa[1];
    bf16x8 af;
    af[0] = f2bf(a0.x); af[1] = f2bf(a0.y); af[2] = f2bf(a0.z); af[3] = f2bf(a0.w);
    af[4] = f2bf(a1.x); af[5] = f2bf(a1.y); af[6] = f2bf(a1.z); af[7] = f2bf(a1.w);
#pragma unroll
    for (int ct = 0; ct < 10; ++ct) {
      int cc = ct * 16 + lc;
      bf16x8 bfl = *(const bf16x8*)&WlT[cc * 160 + kt * 32 + lq * 8];
      accl[ct] = __builtin_amdgcn_mfma_f32_16x16x32_bf16(af, bfl, accl[ct], 0, 0, 0);
      bf16x8 bfr = *(const bf16x8*)&WrT[cc * 160 + kt * 32 + lq * 8];
      accr[ct] = __builtin_amdgcn_mfma_f32_16x16x32_bf16(af, bfr, accr[ct], 0, 0, 0);
    }
  }
#pragma unroll
  for (int ct = 0; ct < 10; ++ct) {
    int col = ct * 16 + lc;
    float bbl = bl[col], bbr = br[col];
#pragma unroll
    for (int rg = 0; rg < 4; ++rg) {
      int row = row0 + lq * 4 + rg;
      if (row < N_NODES) {
        xl[(size_t)row * 160 + col] = f2bf(accl[ct][rg] + bbl);
        xr[(size_t)row * 160 + col] = f2bf(accr[ct][rg] + bbr);
      }
    }
  }
}

// ---------------- fused attention: ONE 64-thread block (1 wave) per dst node ---
// Round-6 data path verbatim; only the wave->node mapping changed (occupancy:
// no 4-wave straggler coupling; 5.25 KB LDS/block).
__global__ __launch_bounds__(64) void attn_fused(
    const short* __restrict__ eacsr, const int* __restrict__ srcm,
    const short* __restrict__ WeTp, const short* __restrict__ xl, const short* __restrict__ xr,
    const float* __restrict__ att, const float* __restrict__ x,
    const float* __restrict__ b_gat, const float* __restrict__ g1, const float* __restrict__ b1,
    const int* __restrict__ offs,
    float* __restrict__ outb, short* __restrict__ outb_bf)
{
  __shared__ short xt[16][168];
  int lane = threadIdx.x;
  int lq = lane >> 4, lc = lane & 15;
  int i = blockIdx.x;
  int e0 = offs[i], e1 = offs[i + 1];
  short* myt = &xt[0][0];

  int segE[5], segS[5];
#pragma unroll
  for (int p = 0; p < 5; ++p) {
    int g = p * 64 + lane;
    int e = (g * 3277) >> 16;
    segE[p] = e;
    segS[p] = g - e * 20;
  }

  float aggc[10] = {};
  float den[5] = {};
  const f32x4 zero4 = {};

  for (int j0 = e0; j0 < e1; j0 += 16) {
#pragma unroll
    for (int p = 0; p < 5; ++p) {
      int j = j0 + segE[p];
      if (j > e1 - 1) j = e1 - 1;
      int srow = srcm[j];
      bf16x8 v = *(const bf16x8*)&xl[(size_t)srow + segS[p] * 8];
      *(bf16x8*)&myt[segE[p] * 168 + segS[p] * 8] = v;
    }
    bf16x8 af = {};
    if (lq < 2) {
      int jr = min(j0 + lc, e1 - 1);
      af = *(const bf16x8*)&eacsr[(size_t)jr * ED + lq * 8];
    }
    bool ok[4];
#pragma unroll
    for (int rg = 0; rg < 4; ++rg) ok[rg] = (j0 + lq * 4 + rg) < e1;

    float partial[5][4] = {};
#pragma unroll
    for (int half = 0; half < 2; ++half) {
      f32x4 acc[5];
#pragma unroll
      for (int cs = 0; cs < 5; ++cs) {
        int ct = half * 5 + cs;
        bf16x8 bfv = *(const bf16x8*)&WeTp[(ct * 16 + lc) * 32 + lq * 8];
        acc[cs] = __builtin_amdgcn_mfma_f32_16x16x32_bf16(af, bfv, zero4, 0, 0, 0);
      }
#pragma unroll
      for (int cs = 0; cs < 5; ++cs) {
        int ct = half * 5 + cs;
        int col = ct * 16 + lc;
        float attv = att[col];
        float xrv = bf2f(xr[(size_t)i * 160 + col]);
#pragma unroll
        for (int rg = 0; rg < 4; ++rg) {
          float xlv = bf2f(myt[(lq * 4 + rg) * 168 + col]);
          float z = acc[cs][rg] + xlv + xrv;
          z = fmaxf(z, NEG_SLOPE * z);
          partial[ct >> 1][rg] = fmaf(z, attv, partial[ct >> 1][rg]);
        }
      }
    }
#pragma unroll
    for (int hh = 0; hh < 5; ++hh) {
#pragma unroll
      for (int rg = 0; rg < 4; ++rg) {
        float p = partial[hh][rg];
        p += __shfl_xor(p, 1, 64);
        p += __shfl_xor(p, 2, 64);
        p += __shfl_xor(p, 4, 64);
        p += __shfl_xor(p, 8, 64);
        float ex = ok[rg] ? __expf(p) : 0.f;
        den[hh] += ex;
        partial[hh][rg] = ex;
      }
    }
#pragma unroll
    for (int ct = 0; ct < 10; ++ct) {
      int col = ct * 16 + lc;
#pragma unroll
      for (int rg = 0; rg < 4; ++rg) {
        float xlv = bf2f(myt[(lq * 4 + rg) * 168 + col]);
        aggc[ct] = fmaf(partial[ct >> 1][rg], xlv, aggc[ct]);
      }
    }
  }
#pragma unroll
  for (int ct = 0; ct < 10; ++ct) {
    aggc[ct] += __shfl_xor(aggc[ct], 16, 64);
    aggc[ct] += __shfl_xor(aggc[ct], 32, 64);
  }
#pragma unroll
  for (int hh = 0; hh < 5; ++hh) {
    den[hh] += __shfl_xor(den[hh], 16, 64);
    den[hh] += __shfl_xor(den[hh], 32, 64);
  }
  float val[10];
  float s1 = 0.f, s2 = 0.f;
#pragma unroll
  for (int ct = 0; ct < 10; ++ct) {
    float d = den[ct >> 1];
    float attn = (d > 0.f) ? aggc[ct] / d : 0.f;
    float v = x[(size_t)i * 160 + ct * 16 + lc] + attn + b_gat[ct * 16 + lc];
    val[ct] = v;
    s1 += v; s2 += v * v;
  }
#pragma unroll
  for (int m = 1; m <= 8; m <<= 1) { s1 += __shfl_xor(s1, m, 64); s2 += __shfl_xor(s2, m, 64); }
  float mu = s1 * (1.f / 160.f);
  float var = s2 * (1.f / 160.f) - mu * mu;
  float rstd = rsqrtf(var + EPS);
  if (lq == 0) {
#pragma unroll
    for (int ct = 0; ct < 10; ++ct) {
      int col = ct * 16 + lc;
      float o = (val[ct] - mu) * rstd * g1[col] + b1[col];
      outb[(size_t)i * 160 + col] = o;
      outb_bf[(size_t)i * 160 + col] = f2bf(o);
    }
  }
}

// ---------------- mlp1: h = LN(selu(outb@Wm1+b)) -> bf16 ----------------
__global__ __launch_bounds__(256) void mlp1_mfma(
    const short* __restrict__ ab, const short* __restrict__ W1T,
    const float* __restrict__ b1m, const float* __restrict__ gm, const float* __restrict__ bm,
    short* __restrict__ h)
{
  __shared__ float ps1[4][16], ps2[4][16];
  int t = threadIdx.x;
  int wave = t >> 6, lane = t & 63;
  int lq = lane >> 4, lc = lane & 15;
  int row0 = blockIdx.x * 16;
  f32x4 acc[8] = {};
#pragma unroll
  for (int kt = 0; kt < 5; ++kt) {
    bf16x8 af = *(const bf16x8*)&ab[(size_t)(row0 + lc) * 160 + kt * 32 + lq * 8];
#pragma unroll
    for (int ct = 0; ct < 8; ++ct) {
      int cc = wave * 128 + ct * 16 + lc;
      bf16x8 bfv = *(const bf16x8*)&W1T[cc * 160 + kt * 32 + lq * 8];
      acc[ct] = __builtin_amdgcn_mfma_f32_16x16x32_bf16(af, bfv, acc[ct], 0, 0, 0);
    }
  }
  float s1[4] = {}, s2[4] = {};
#pragma unroll
  for (int ct = 0; ct < 8; ++ct) {
    int cc = wave * 128 + ct * 16 + lc;
    float bb = b1m[cc];
#pragma unroll
    for (int rg = 0; rg < 4; ++rg) {
      float v = selu_f(acc[ct][rg] + bb);
      acc[ct][rg] = v;
      s1[rg] += v; s2[rg] += v * v;
    }
  }
#pragma unroll
  for (int m = 1; m <= 8; m <<= 1) {
#pragma unroll
    for (int rg = 0; rg < 4; ++rg) {
      s1[rg] += __shfl_xor(s1[rg], m, 64);
      s2[rg] += __shfl_xor(s2[rg], m, 64);
    }
  }
  if (lc == 0) {
#pragma unroll
    for (int rg = 0; rg < 4; ++rg) {
      ps1[wave][lq * 4 + rg] = s1[rg];
      ps2[wave][lq * 4 + rg] = s2[rg];
    }
  }
  __syncthreads();
  float mu[4], rstd[4];
#pragma unroll
  for (int rg = 0; rg < 4; ++rg) {
    int rl = lq * 4 + rg;
    float a = ps1[0][rl] + ps1[1][rl] + ps1[2][rl] + ps1[3][rl];
    float b = ps2[0][rl] + ps2[1][rl] + ps2[2][rl] + ps2[3][rl];
    float m_ = a * (1.f / 512.f);
    float var = b * (1.f / 512.f) - m_ * m_;
    mu[rg] = m_; rstd[rg] = rsqrtf(var + EPS);
  }
#pragma unroll
  for (int ct = 0; ct < 8; ++ct) {
    int cc = wave * 128 + ct * 16 + lc;
    float gg = gm[cc], bb = bm[cc];
#pragma unroll
    for (int rg = 0; rg < 4; ++rg) {
      int row = row0 + lq * 4 + rg;
      h[(size_t)row * 512 + cc] = f2bf((acc[ct][rg] - mu[rg]) * rstd[rg] * gg + bb);
    }
  }
}

// ---------------- mlp2: y = LN(outb + h@Wm2 + b) ----------------
__global__ __launch_bounds__(256) void mlp2_mfma(
    const short* __restrict__ hb, const short* __restrict__ W2T,
    const float* __restrict__ b2m, const float* __restrict__ outb,
    const float* __restrict__ g2, const float* __restrict__ b2,
    float* __restrict__ y)
{
  int t = threadIdx.x;
  int wave = t >> 6, lane = t & 63;
  int lq = lane >> 4, lc = lane & 15;
  int row0 = blockIdx.x * 64 + wave * 16;
  f32x4 acc[10] = {};
#pragma unroll
  for (int kt = 0; kt < 16; ++kt) {
    int gr = min(row0 + lc, N_NODES - 1);
    bf16x8 af = *(const bf16x8*)&hb[(size_t)gr * 512 + kt * 32 + lq * 8];
#pragma unroll
    for (int ct = 0; ct < 10; ++ct) {
      bf16x8 bfv = *(const bf16x8*)&W2T[(ct * 16 + lc) * 512 + kt * 32 + lq * 8];
      acc[ct] = __builtin_amdgcn_mfma_f32_16x16x32_bf16(af, bfv, acc[ct], 0, 0, 0);
    }
  }
  float s1[4] = {}, s2[4] = {};
#pragma unroll
  for (int ct = 0; ct < 10; ++ct) {
    int col = ct * 16 + lc;
#pragma unroll
    for (int rg = 0; rg < 4; ++rg) {
      int rowl = min(row0 + lq * 4 + rg, N_NODES - 1);
      float v = acc[ct][rg] + b2m[col] + outb[(size_t)rowl * 160 + col];
      acc[ct][rg] = v;
      s1[rg] += v; s2[rg] += v * v;
    }
  }
#pragma unroll
  for (int m = 1; m <= 8; m <<= 1) {
#pragma unroll
    for (int rg = 0; rg < 4; ++rg) {
      s1[rg] += __shfl_xor(s1[rg], m, 64);
      s2[rg] += __shfl_xor(s2[rg], m, 64);
    }
  }
  float mu[4], rstd[4];
#pragma unroll
  for (int rg = 0; rg < 4; ++rg) {
    float m_ = s1[rg] * (1.f / 160.f);
    float var = s2[rg] * (1.f / 160.f) - m_ * m_;
    mu[rg] = m_; rstd[rg] = rsqrtf(var + EPS);
  }
#pragma unroll
  for (int ct = 0; ct < 10; ++ct) {
    int col = ct * 16 + lc;
#pragma unroll
    for (int rg = 0; rg < 4; ++rg) {
      int row = row0 + lq * 4 + rg;
      if (row < N_NODES)
        y[(size_t)row * 160 + col] = (acc[ct][rg] - mu[rg]) * rstd[rg] * g2[col] + b2[col];
    }
  }
}

extern "C" void kernel_launch(void* const* d_in, const int* in_sizes, int n_in,
                              void* d_out, int out_size, void* d_ws, size_t ws_size,
                              hipStream_t stream) {
  const float* x     = (const float*)d_in[0];
  const int*   ei    = (const int*)d_in[1];
  const float* eattr = (const float*)d_in[2];
  const float* Wl    = (const float*)d_in[5];
  const float* bl    = (const float*)d_in[6];
  const float* Wr    = (const float*)d_in[7];
  const float* br    = (const float*)d_in[8];
  const float* We    = (const float*)d_in[9];
  const float* att   = (const float*)d_in[10];
  const float* bgat  = (const float*)d_in[11];
  const float* g1    = (const float*)d_in[12];
  const float* b1    = (const float*)d_in[13];
  const float* Wm1   = (const float*)d_in[14];
  const float* bm1   = (const float*)d_in[15];
  const float* gm    = (const float*)d_in[16];
  const float* bm    = (const float*)d_in[17];
  const float* Wm2   = (const float*)d_in[18];
  const float* bm2   = (const float*)d_in[19];
  const float* g2    = (const float*)d_in[20];
  const float* b2    = (const float*)d_in[21];
  float* y = (float*)d_out;

  char* p = (char*)d_ws;
  auto alloc = [&](size_t bytes) {
    void* q = p;
    p += (bytes + 255) & ~(size_t)255;
    return q;
  };
  short* xlb     = (short*)alloc((size_t)N_NODES * 160 * 2);
  short* xrb     = (short*)alloc((size_t)N_NODES * 160 * 2);
  float* outb    = (float*)alloc((size_t)N_NODES * 160 * 4);
  short* outb_bf = (short*)alloc((size_t)N_NODES * 160 * 2);
  short* hb      = (short*)alloc((size_t)N_NODES * 512 * 2);
  short* eacsr   = (short*)alloc((size_t)E_EDGES * ED * 2);
  int*   srcm    = (int*)alloc((size_t)E_EDGES * 4);
  short* WlT     = (short*)alloc(160 * 160 * 2);
  short* WrT     = (short*)alloc(160 * 160 * 2);
  short* W1T     = (short*)alloc(512 * 160 * 2);
  short* W2T     = (short*)alloc(160 * 512 * 2);
  short* WeTp    = (short*)alloc(160 * 32 * 2);
  int*   cnt     = (int*)alloc((size_t)N_NODES * 4);
  int*   offs    = (int*)alloc((size_t)(N_NODES + 1) * 4);
  int*   cursor  = (int*)alloc((size_t)N_NODES * 4);
  int*   pinc    = (int*)alloc((size_t)N_NODES * 4);
  int*   bsum    = (int*)alloc(64 * 4);
  int*   boff    = (int*)alloc(64 * 4);

  hipMemsetAsync(cnt, 0, (size_t)N_NODES * 4, stream);
  hipMemsetAsync(cursor, 0, (size_t)N_NODES * 4, stream);

  prep_weights<<<(220160 + 255) / 256, 256, 0, stream>>>(Wl, Wr, Wm1, Wm2, We,
                                                         WlT, WrT, W1T, W2T, WeTp);
  count_kernel<<<(E_EDGES + 255) / 256, 256, 0, stream>>>(ei, cnt);
  scanA<<<49, 1024, 0, stream>>>(cnt, pinc, bsum);
  scanB<<<1, 64, 0, stream>>>(bsum, boff);
  scanC<<<49, 1024, 0, stream>>>(pinc, boff, offs);
  scatter3<<<(E_EDGES + 255) / 256, 256, 0, stream>>>(ei, eattr, offs, cursor, srcm, eacsr);
  proj_mfma<<<(N_NODES + 63) / 64, 256, 0, stream>>>(x, WlT, WrT, bl, br, xlb, xrb);
  attn_fused<<<N_NODES, 64, 0, stream>>>(eacsr, srcm, WeTp, xlb, xrb, att, x,
                                         bgat, g1, b1, offs, outb, outb_bf);
  mlp1_mfma<<<N_NODES / 16, 256, 0, stream>>>(outb_bf, W1T, bm1, gm, bm, hb);
  mlp2_mfma<<<(N_NODES + 63) / 64, 256, 0, stream>>>(hb, W2T, bm2, outb, g2, b2, y);
}